// Round 19
// baseline (87.278 us; speedup 1.0000x reference)
//
#include <hip/hip_runtime.h>

#define SIZE 1024
#define MM 10
#define NTERMS 10

typedef _Float16 f16;
typedef __attribute__((ext_vector_type(8))) _Float16 f16x8;
typedef __attribute__((ext_vector_type(4))) _Float16 f16x4;
typedef __attribute__((ext_vector_type(4))) float    f32x4;
typedef __attribute__((ext_vector_type(2))) int      i2;

typedef const __attribute__((address_space(1))) _Float16 gf16;  // global
typedef __attribute__((address_space(3))) _Float16 sf16;        // LDS

__device__ __forceinline__ float4 ldq(const float* p) { return *(const float4*)p; }

#define FMA4F(W, v0, v1, v2, v3)                                     \
    a0 = fmaf((W)[0], (v0), a0); a1 = fmaf((W)[1], (v1), a1);        \
    a2 = fmaf((W)[2], (v2), a2); a3 = fmaf((W)[3], (v3), a3);

__device__ __forceinline__ void cvt16(const float4& v0, const float4& v1, f16x8& h) {
    h[0] = (f16)v0.x; h[1] = (f16)v0.y; h[2] = (f16)v0.z; h[3] = (f16)v0.w;
    h[4] = (f16)v1.x; h[5] = (f16)v1.y; h[6] = (f16)v1.z; h[7] = (f16)v1.w;
}

// ===========================================================================
// Kernel 1 (R19): STENCIL ONLY. Cross-round subtraction (R7: stencil ~15us
// alone; R13/R18: stencil+cvt fused = 33-47us) shows fusing cvt INTO the
// stencil kernel is the pre-chain fat: cvt blocks inherit 16KB LDS + 128
// VGPR and queue in a shared-occupancy kernel. cvt moves to trans_cvt.
// Body = R18's proven stencil branch (coalesced row-major G16 write).
// ===========================================================================
__global__ __launch_bounds__(256, 2)
void precompute_G16(const float* __restrict__ diag,
                    const float* __restrict__ subpad,
                    const float* __restrict__ suppad,
                    const float* __restrict__ logit,
                    f16* __restrict__ G16)   // [k][s] row-major
{
    __shared__ float buf[2][2][SIZE];     // 16 KB

    const int tid = threadIdx.x;
    const int s0  = tid * 4;
    const int rowbase = blockIdx.x * 2;   // 512 blocks x 2 identity rows

    #pragma unroll
    for (int r = 0; r < 2; ++r) {
        float4 v;
        v.x = (rowbase + r == s0 + 0) ? 1.f : 0.f;
        v.y = (rowbase + r == s0 + 1) ? 1.f : 0.f;
        v.z = (rowbase + r == s0 + 2) ? 1.f : 0.f;
        v.w = (rowbase + r == s0 + 3) ? 1.f : 0.f;
        *(float4*)&buf[0][r][s0] = v;
    }
    __syncthreads();

    int cur = 0;
    for (int t = 0; t < NTERMS; ++t) {
        const int i = NTERMS - 1 - t;

        float lg[MM];
        float mx = -3.4e38f;
        #pragma unroll
        for (int j = 0; j < MM; ++j) { lg[j] = logit[i * MM + j]; mx = fmaxf(mx, lg[j]); }
        float ssum = 0.f;
        #pragma unroll
        for (int j = 0; j < MM; ++j) { lg[j] = __expf(lg[j] - mx); ssum += lg[j]; }
        const float inv = 1.0f / ssum;

        float D[4] = {0.f, 0.f, 0.f, 0.f};
        float Wsb[MM][4], Wsp[MM][4];
        #pragma unroll
        for (int j = 0; j < MM; ++j) {
            const float pj = lg[j] * inv;
            const float4 dg = ldq(diag   + j * SIZE + s0);
            const float4 sb = ldq(subpad + j * SIZE + s0);
            const float4 sp = ldq(suppad + j * SIZE + s0);
            D[0] = fmaf(pj, dg.x, D[0]); D[1] = fmaf(pj, dg.y, D[1]);
            D[2] = fmaf(pj, dg.z, D[2]); D[3] = fmaf(pj, dg.w, D[3]);
            Wsb[j][0] = pj * sb.x; Wsb[j][1] = pj * sb.y;
            Wsb[j][2] = pj * sb.z; Wsb[j][3] = pj * sb.w;
            Wsp[j][0] = pj * sp.x; Wsp[j][1] = pj * sp.y;
            Wsp[j][2] = pj * sp.z; Wsp[j][3] = pj * sp.w;
        }

        const bool last = (t == NTERMS - 1);
        for (int r = 0; r < 2; ++r) {
            const float* row = &buf[cur][r][0];

            const float4 xo = ldq(row + s0);
            float a0 = D[0] * xo.x, a1 = D[1] * xo.y,
                  a2 = D[2] * xo.z, a3 = D[3] * xo.w;

            const float4 xl = ldq(row + (s0 >= 4         ? s0 - 4 : 0));
            const float4 xr = ldq(row + (s0 + 4 <= 1020  ? s0 + 4 : 1020));

            FMA4F(Wsb[9], xl.w, xo.x, xo.y, xo.z)
            FMA4F(Wsp[9], xo.y, xo.z, xo.w, xr.x)
            FMA4F(Wsb[8], xl.z, xl.w, xo.x, xo.y)
            FMA4F(Wsp[8], xo.z, xo.w, xr.x, xr.y)
            FMA4F(Wsb[7], xl.x, xl.y, xl.z, xl.w)
            FMA4F(Wsp[7], xr.x, xr.y, xr.z, xr.w)
            #pragma unroll
            for (int j = 0; j <= 6; ++j) {
                const int d = 512 >> j;
                const float4 xm = ldq(row + (s0 >= d        ? s0 - d : 0));
                const float4 xp = ldq(row + (s0 + d <= 1020 ? s0 + d : 1020));
                FMA4F(Wsb[j], xm.x, xm.y, xm.z, xm.w)
                FMA4F(Wsp[j], xp.x, xp.y, xp.z, xp.w)
            }

            if (last) {
                const int k = rowbase + r;
                f16x4 h;
                h[0] = (f16)a0; h[1] = (f16)a1; h[2] = (f16)a2; h[3] = (f16)a3;
                *(f16x4*)(G16 + (long)k * SIZE + s0) = h;
            } else {
                *(float4*)&buf[cur ^ 1][r][s0] = make_float4(a0, a1, a2, a3);
            }
        }
        __syncthreads();
        cur ^= 1;
    }
}

// ===========================================================================
// Kernel 2 (R19): transpose + cvt paired — both pure-bandwidth, mutually
// independent (transpose needs G16, cvt needs only x). Blocks 0..255:
// Gt[s][k] = G16[k][s] (R18's proven 64x64 tile). Blocks 256..2303:
// xh = f16(x). Combined ~72MB of traffic overlaps to ~11-13us.
// ===========================================================================
__global__ __launch_bounds__(256)
void trans_cvt(const f16* __restrict__ G16, f16* __restrict__ Gt,
               const float* __restrict__ x, f16* __restrict__ xh)
{
    __shared__ float tile[64][65];
    const int tid = threadIdx.x;
    const int bid = blockIdx.x;

    if (bid >= 256) {
        // ---- cvt branch: xh = f16(x), cvt block 0..2047 ----
        const long i = ((long)(bid - 256) * 256 + tid) * 16;
        const float4 a = ldq(x + i), b = ldq(x + i + 4),
                     c = ldq(x + i + 8), d = ldq(x + i + 12);
        f16x8 h0, h1; cvt16(a, b, h0); cvt16(c, d, h1);
        *(f16x8*)(xh + i)     = h0;
        *(f16x8*)(xh + i + 8) = h1;
        return;
    }

    // ---- transpose branch (R18-proven; f16->f32->f16 is bit-exact) ----
    const int k0 = (bid & 15) * 64;
    const int s0 = (bid >> 4) * 64;
    const int rr = tid >> 4;          // 0..15
    const int cc = (tid & 15) * 4;    // 0..60

    #pragma unroll
    for (int p = 0; p < 4; ++p) {
        const f16x4 v = *(const f16x4*)(G16 + (long)(k0 + rr + p * 16) * SIZE + s0 + cc);
        tile[rr + p * 16][cc + 0] = (float)v[0];
        tile[rr + p * 16][cc + 1] = (float)v[1];
        tile[rr + p * 16][cc + 2] = (float)v[2];
        tile[rr + p * 16][cc + 3] = (float)v[3];
    }
    __syncthreads();
    #pragma unroll
    for (int p = 0; p < 4; ++p) {
        const int s = rr + p * 16;
        f16x4 h;
        h[0] = (f16)tile[cc + 0][s];
        h[1] = (f16)tile[cc + 1][s];
        h[2] = (f16)tile[cc + 2][s];
        h[3] = (f16)tile[cc + 3][s];
        *(f16x4*)(Gt + (long)(s0 + s) * SIZE + k0 + cc) = h;
    }
}

// ===========================================================================
// GEMM (R19 = R15 verbatim, measured-best 46.4us): 4-wave 128x128, BK=64,
// gload_lds A-staging with rule-#21 both-sides swizzle (conflicts 0),
// B double-buffered in named regs from global (L2-resident Gt), bm-XCD
// swizzle. Plateau kernel across R12-R16 variations.
// ===========================================================================
#define BMT 128
#define BNT 128
#define BKT 64
#define NKT (1024 / BKT)   // 16

__global__ __launch_bounds__(256, 2)
void gemm_f16(const f16* __restrict__ xh,
              const f16* __restrict__ Gt,
              float* __restrict__ out)
{
    __shared__ f16 Xs[2][BMT][BKT];    // 32 KB, linear (gload_lds dest)

    const int tid  = threadIdx.x;
    const int bm   = blockIdx.x & 63;          // same-bm -> same XCD (64%8==0)
    const int bn   = blockIdx.x >> 6;          // 0..7
    const int w    = tid >> 6, lane = tid & 63;
    const int wm   = w >> 1,  wn   = w & 1;
    const int lr   = lane & 15, lk = lane >> 4;
    const int sw   = lr & 7;                   // read-side swizzle key

    const int srow = (tid >> 6) * 8 + ((tid >> 3) & 7);
    const int scol = (((tid & 7) ^ ((tid >> 3) & 7))) * 8;
    const f16* gsrc = xh + (long)(bm * BMT + srow) * 1024 + scol;

    const f16* gbase = Gt + (long)(bn * BNT + wn * 64 + lr) * 1024 + lk * 8;

    f32x4 acc[4][4];
    #pragma unroll
    for (int mi = 0; mi < 4; ++mi)
        #pragma unroll
        for (int ni = 0; ni < 4; ++ni)
            acc[mi][ni] = (f32x4){0.f, 0.f, 0.f, 0.f};

    f16x8 bE0, bE1, bE2, bE3, bE4, bE5, bE6, bE7;
    f16x8 bO0, bO1, bO2, bO3, bO4, bO5, bO6, bO7;

#define STAGE(BUF, KT) {                                                      \
        const f16* gp = gsrc + (KT) * BKT;                                    \
        sf16* lp = (sf16*)&Xs[0][0][0] + (BUF) * 8192 + (tid >> 6) * 512;     \
        __builtin_amdgcn_global_load_lds((gf16*)gp,               lp,        16, 0, 0); \
        __builtin_amdgcn_global_load_lds((gf16*)(gp + 32 * 1024), lp + 2048, 16, 0, 0); \
        __builtin_amdgcn_global_load_lds((gf16*)(gp + 64 * 1024), lp + 4096, 16, 0, 0); \
        __builtin_amdgcn_global_load_lds((gf16*)(gp + 96 * 1024), lp + 6144, 16, 0, 0); }
#define LOADB(S, KT) {                                                \
        const f16* gp = gbase + (KT) * BKT;                           \
        S##0 = *(const f16x8*)(gp);                                   \
        S##1 = *(const f16x8*)(gp + 32);                              \
        S##2 = *(const f16x8*)(gp + 16 * 1024);                       \
        S##3 = *(const f16x8*)(gp + 16 * 1024 + 32);                  \
        S##4 = *(const f16x8*)(gp + 32 * 1024);                       \
        S##5 = *(const f16x8*)(gp + 32 * 1024 + 32);                  \
        S##6 = *(const f16x8*)(gp + 48 * 1024);                       \
        S##7 = *(const f16x8*)(gp + 48 * 1024 + 32); }
#define COMPUTE(BUF, S) {                                                     \
        const f16* base = (const f16*)&Xs[0][0][0] + (BUF) * 8192;            \
        const int rb = (wm * 64 + lr) * 64;                                   \
        const int s0e = ((lk     ^ sw) * 8);                                  \
        const int s1e = (((4 + lk) ^ sw) * 8);                                \
        f16x8 a0 = *(const f16x8*)(base + rb +    0      + s0e);              \
        f16x8 a1 = *(const f16x8*)(base + rb + 16 * 64   + s0e);              \
        f16x8 a2 = *(const f16x8*)(base + rb + 32 * 64   + s0e);              \
        f16x8 a3 = *(const f16x8*)(base + rb + 48 * 64   + s0e);              \
        acc[0][0] = __builtin_amdgcn_mfma_f32_16x16x32_f16(a0, S##0, acc[0][0], 0, 0, 0); \
        acc[0][1] = __builtin_amdgcn_mfma_f32_16x16x32_f16(a0, S##2, acc[0][1], 0, 0, 0); \
        acc[0][2] = __builtin_amdgcn_mfma_f32_16x16x32_f16(a0, S##4, acc[0][2], 0, 0, 0); \
        acc[0][3] = __builtin_amdgcn_mfma_f32_16x16x32_f16(a0, S##6, acc[0][3], 0, 0, 0); \
        acc[1][0] = __builtin_amdgcn_mfma_f32_16x16x32_f16(a1, S##0, acc[1][0], 0, 0, 0); \
        acc[1][1] = __builtin_amdgcn_mfma_f32_16x16x32_f16(a1, S##2, acc[1][1], 0, 0, 0); \
        acc[1][2] = __builtin_amdgcn_mfma_f32_16x16x32_f16(a1, S##4, acc[1][2], 0, 0, 0); \
        acc[1][3] = __builtin_amdgcn_mfma_f32_16x16x32_f16(a1, S##6, acc[1][3], 0, 0, 0); \
        acc[2][0] = __builtin_amdgcn_mfma_f32_16x16x32_f16(a2, S##0, acc[2][0], 0, 0, 0); \
        acc[2][1] = __builtin_amdgcn_mfma_f32_16x16x32_f16(a2, S##2, acc[2][1], 0, 0, 0); \
        acc[2][2] = __builtin_amdgcn_mfma_f32_16x16x32_f16(a2, S##4, acc[2][2], 0, 0, 0); \
        acc[2][3] = __builtin_amdgcn_mfma_f32_16x16x32_f16(a2, S##6, acc[2][3], 0, 0, 0); \
        acc[3][0] = __builtin_amdgcn_mfma_f32_16x16x32_f16(a3, S##0, acc[3][0], 0, 0, 0); \
        acc[3][1] = __builtin_amdgcn_mfma_f32_16x16x32_f16(a3, S##2, acc[3][1], 0, 0, 0); \
        acc[3][2] = __builtin_amdgcn_mfma_f32_16x16x32_f16(a3, S##4, acc[3][2], 0, 0, 0); \
        acc[3][3] = __builtin_amdgcn_mfma_f32_16x16x32_f16(a3, S##6, acc[3][3], 0, 0, 0); \
        a0 = *(const f16x8*)(base + rb +    0      + s1e);                    \
        a1 = *(const f16x8*)(base + rb + 16 * 64   + s1e);                    \
        a2 = *(const f16x8*)(base + rb + 32 * 64   + s1e);                    \
        a3 = *(const f16x8*)(base + rb + 48 * 64   + s1e);                    \
        acc[0][0] = __builtin_amdgcn_mfma_f32_16x16x32_f16(a0, S##1, acc[0][0], 0, 0, 0); \
        acc[0][1] = __builtin_amdgcn_mfma_f32_16x16x32_f16(a0, S##3, acc[0][1], 0, 0, 0); \
        acc[0][2] = __builtin_amdgcn_mfma_f32_16x16x32_f16(a0, S##5, acc[0][2], 0, 0, 0); \
        acc[0][3] = __builtin_amdgcn_mfma_f32_16x16x32_f16(a0, S##7, acc[0][3], 0, 0, 0); \
        acc[1][0] = __builtin_amdgcn_mfma_f32_16x16x32_f16(a1, S##1, acc[1][0], 0, 0, 0); \
        acc[1][1] = __builtin_amdgcn_mfma_f32_16x16x32_f16(a1, S##3, acc[1][1], 0, 0, 0); \
        acc[1][2] = __builtin_amdgcn_mfma_f32_16x16x32_f16(a1, S##5, acc[1][2], 0, 0, 0); \
        acc[1][3] = __builtin_amdgcn_mfma_f32_16x16x32_f16(a1, S##7, acc[1][3], 0, 0, 0); \
        acc[2][0] = __builtin_amdgcn_mfma_f32_16x16x32_f16(a2, S##1, acc[2][0], 0, 0, 0); \
        acc[2][1] = __builtin_amdgcn_mfma_f32_16x16x32_f16(a2, S##3, acc[2][1], 0, 0, 0); \
        acc[2][2] = __builtin_amdgcn_mfma_f32_16x16x32_f16(a2, S##5, acc[2][2], 0, 0, 0); \
        acc[2][3] = __builtin_amdgcn_mfma_f32_16x16x32_f16(a2, S##7, acc[2][3], 0, 0, 0); \
        acc[3][0] = __builtin_amdgcn_mfma_f32_16x16x32_f16(a3, S##1, acc[3][0], 0, 0, 0); \
        acc[3][1] = __builtin_amdgcn_mfma_f32_16x16x32_f16(a3, S##3, acc[3][1], 0, 0, 0); \
        acc[3][2] = __builtin_amdgcn_mfma_f32_16x16x32_f16(a3, S##5, acc[3][2], 0, 0, 0); \
        acc[3][3] = __builtin_amdgcn_mfma_f32_16x16x32_f16(a3, S##7, acc[3][3], 0, 0, 0); }

    STAGE(0, 0); LOADB(bE, 0);
    __syncthreads();

    #pragma unroll 1
    for (int kt2 = 0; kt2 < NKT / 2; ++kt2) {
        const int kt = kt2 * 2;
        STAGE(1, kt + 1);
        LOADB(bO, kt + 1);
        COMPUTE(0, bE);
        __syncthreads();
        if (kt2 < NKT / 2 - 1) {
            STAGE(0, kt + 2);
            LOADB(bE, kt + 2);
        }
        COMPUTE(1, bO);
        __syncthreads();
    }

    const long orow0 = (long)bm * BMT + wm * 64 + lk * 4;
    const int  ocol0 = bn * BNT + wn * 64 + lr;
    #pragma unroll
    for (int mi = 0; mi < 4; ++mi)
        #pragma unroll
        for (int ni = 0; ni < 4; ++ni)
            #pragma unroll
            for (int q = 0; q < 4; ++q)
                out[(orow0 + mi * 16 + q) * 1024 + ocol0 + ni * 16] = acc[mi][ni][q];

#undef STAGE
#undef LOADB
#undef COMPUTE
}

// ===========================================================================
// Fallback (ws too small): R6's proven stencil kernel.
// ===========================================================================
#define RPB 16
#define MIX_L(acc, r32, ww) \
    asm("v_fma_mix_f32 %0, %1, %2, %0 op_sel:[0,0,0] op_sel_hi:[1,0,0]" \
        : "+v"(acc) : "v"(r32), "v"(ww))
#define MIX_H(acc, r32, ww) \
    asm("v_fma_mix_f32 %0, %1, %2, %0 op_sel:[1,0,0] op_sel_hi:[1,0,0]" \
        : "+v"(acc) : "v"(r32), "v"(ww))

__global__ __launch_bounds__(256, 2)
void butterfly_h16mix(const float* __restrict__ x,
                      const float* __restrict__ diag,
                      const float* __restrict__ subpad,
                      const float* __restrict__ suppad,
                      const float* __restrict__ logit,
                      float* __restrict__ out)
{
    __shared__ f16 buf[2][RPB][SIZE];
    const int tid = threadIdx.x;
    const int s0  = tid * 4;
    const long rowbase = (long)blockIdx.x * RPB;

    #pragma unroll
    for (int r = 0; r < RPB; ++r) {
        const float4 v = ldq(x + (rowbase + r) * SIZE + s0);
        f16x4 h;
        h[0] = (f16)v.x; h[1] = (f16)v.y; h[2] = (f16)v.z; h[3] = (f16)v.w;
        *(f16x4*)&buf[0][r][s0] = h;
    }
    __syncthreads();

    int cur = 0;
    for (int t = 0; t < NTERMS; ++t) {
        const int i = NTERMS - 1 - t;
        float lg[MM];
        float mx = -3.4e38f;
        #pragma unroll
        for (int j = 0; j < MM; ++j) { lg[j] = logit[i * MM + j]; mx = fmaxf(mx, lg[j]); }
        float ssum = 0.f;
        #pragma unroll
        for (int j = 0; j < MM; ++j) { lg[j] = __expf(lg[j] - mx); ssum += lg[j]; }
        const float inv = 1.0f / ssum;

        float D[4] = {0.f, 0.f, 0.f, 0.f};
        float Wsb[MM][4], Wsp[MM][4];
        #pragma unroll
        for (int j = 0; j < MM; ++j) {
            const float pj = lg[j] * inv;
            const float4 dg = ldq(diag   + j * SIZE + s0);
            const float4 sb = ldq(subpad + j * SIZE + s0);
            const float4 sp = ldq(suppad + j * SIZE + s0);
            D[0] = fmaf(pj, dg.x, D[0]); D[1] = fmaf(pj, dg.y, D[1]);
            D[2] = fmaf(pj, dg.z, D[2]); D[3] = fmaf(pj, dg.w, D[3]);
            Wsb[j][0] = pj * sb.x; Wsb[j][1] = pj * sb.y;
            Wsb[j][2] = pj * sb.z; Wsb[j][3] = pj * sb.w;
            Wsp[j][0] = pj * sp.x; Wsp[j][1] = pj * sp.y;
            Wsp[j][2] = pj * sp.z; Wsp[j][3] = pj * sp.w;
        }

        const bool last = (t == NTERMS - 1);
        for (int r = 0; r < RPB; ++r) {
            const f16* row = &buf[cur][r][0];
            const i2 xo = *(const i2*)&row[s0];
            const i2 xl = *(const i2*)&row[(s0 >= 4)        ? s0 - 4 : 0];
            const i2 xr = *(const i2*)&row[(s0 + 4 <= 1020) ? s0 + 4 : 1020];
            float a0 = 0.f, a1 = 0.f, a2 = 0.f, a3 = 0.f;

            MIX_L(a0, xo.x, D[0]); MIX_H(a1, xo.x, D[1]);
            MIX_L(a2, xo.y, D[2]); MIX_H(a3, xo.y, D[3]);
            MIX_H(a0, xl.y, Wsb[9][0]); MIX_L(a1, xo.x, Wsb[9][1]);
            MIX_H(a2, xo.x, Wsb[9][2]); MIX_L(a3, xo.y, Wsb[9][3]);
            MIX_H(a0, xo.x, Wsp[9][0]); MIX_L(a1, xo.y, Wsp[9][1]);
            MIX_H(a2, xo.y, Wsp[9][2]); MIX_L(a3, xr.x, Wsp[9][3]);
            MIX_L(a0, xl.y, Wsb[8][0]); MIX_H(a1, xl.y, Wsb[8][1]);
            MIX_L(a2, xo.x, Wsb[8][2]); MIX_H(a3, xo.x, Wsb[8][3]);
            MIX_L(a0, xo.y, Wsp[8][0]); MIX_H(a1, xo.y, Wsp[8][1]);
            MIX_L(a2, xr.x, Wsp[8][2]); MIX_H(a3, xr.x, Wsp[8][3]);
            MIX_L(a0, xl.x, Wsb[7][0]); MIX_H(a1, xl.x, Wsb[7][1]);
            MIX_L(a2, xl.y, Wsb[7][2]); MIX_H(a3, xl.y, Wsb[7][3]);
            MIX_L(a0, xr.x, Wsp[7][0]); MIX_H(a1, xr.x, Wsp[7][1]);
            MIX_L(a2, xr.y, Wsp[7][2]); MIX_H(a3, xr.y, Wsp[7][3]);
            #pragma unroll
            for (int j = 0; j <= 6; ++j) {
                const int d = 512 >> j;
                const i2 xm = *(const i2*)&row[(s0 >= d)        ? s0 - d : 0];
                const i2 xp = *(const i2*)&row[(s0 + d <= 1020) ? s0 + d : 1020];
                MIX_L(a0, xm.x, Wsb[j][0]); MIX_H(a1, xm.x, Wsb[j][1]);
                MIX_L(a2, xm.y, Wsb[j][2]); MIX_H(a3, xm.y, Wsb[j][3]);
                MIX_L(a0, xp.x, Wsp[j][0]); MIX_H(a1, xp.x, Wsp[j][1]);
                MIX_L(a2, xp.y, Wsp[j][2]); MIX_H(a3, xp.y, Wsp[j][3]);
            }

            if (last) {
                *(float4*)(out + (rowbase + r) * SIZE + s0) =
                    make_float4(a0, a1, a2, a3);
            } else {
                f16x4 hv;
                hv[0] = (f16)a0; hv[1] = (f16)a1; hv[2] = (f16)a2; hv[3] = (f16)a3;
                *(f16x4*)&buf[cur ^ 1][r][s0] = hv;
            }
        }
        __syncthreads();
        cur ^= 1;
    }
}

extern "C" void kernel_launch(void* const* d_in, const int* in_sizes, int n_in,
                              void* d_out, int out_size, void* d_ws, size_t ws_size,
                              hipStream_t stream) {
    const float* x      = (const float*)d_in[0];
    const float* diag   = (const float*)d_in[1];
    const float* subpad = (const float*)d_in[2];
    const float* suppad = (const float*)d_in[3];
    const float* logit  = (const float*)d_in[4];
    float* outp = (float*)d_out;

    const int batch = in_sizes[0] / SIZE;                        // 8192
    const size_t needG16 = (size_t)SIZE * SIZE * sizeof(f16);    // 2 MB
    const size_t needGt  = (size_t)SIZE * SIZE * sizeof(f16);    // 2 MB
    const size_t needXh  = (size_t)batch * SIZE * sizeof(f16);   // 16 MB

    if (d_ws != nullptr && ws_size >= needG16 + needGt + needXh) {
        f16* G16 = (f16*)d_ws;
        f16* Gt  = (f16*)((char*)d_ws + needG16);
        f16* xh  = (f16*)((char*)d_ws + needG16 + needGt);
        precompute_G16<<<dim3(512), dim3(256), 0, stream>>>(
            diag, subpad, suppad, logit, G16);
        const int cvtBlocks = (int)(((long)batch * SIZE) / (256 * 16));  // 2048
        trans_cvt<<<dim3(256 + cvtBlocks), dim3(256), 0, stream>>>(
            G16, Gt, x, xh);
        const int nblocks = (batch / BMT) * (SIZE / BNT);        // 512
        gemm_f16<<<dim3(nblocks), dim3(256), 0, stream>>>(xh, Gt, outp);
    } else {
        butterfly_h16mix<<<dim3(batch / RPB), dim3(256), 0, stream>>>(
            x, diag, subpad, suppad, logit, outp);
    }
}

// Round 20
// 85.710 us; speedup vs baseline: 1.0183x; 1.0183x over previous
//
#include <hip/hip_runtime.h>

#define SIZE 1024
#define MM 10
#define NTERMS 10

typedef _Float16 f16;
typedef __attribute__((ext_vector_type(8))) _Float16 f16x8;
typedef __attribute__((ext_vector_type(4))) _Float16 f16x4;
typedef __attribute__((ext_vector_type(4))) float    f32x4;
typedef __attribute__((ext_vector_type(2))) int      i2;

__device__ __forceinline__ float4 ldq(const float* p) { return *(const float4*)p; }

#define FMA4F(W, v0, v1, v2, v3)                                     \
    a0 = fmaf((W)[0], (v0), a0); a1 = fmaf((W)[1], (v1), a1);        \
    a2 = fmaf((W)[2], (v2), a2); a3 = fmaf((W)[3], (v3), a3);

__device__ __forceinline__ void cvt16(const float4& v0, const float4& v1, f16x8& h) {
    h[0] = (f16)v0.x; h[1] = (f16)v0.y; h[2] = (f16)v0.z; h[3] = (f16)v0.w;
    h[4] = (f16)v1.x; h[5] = (f16)v1.y; h[6] = (f16)v1.z; h[7] = (f16)v1.w;
}

// ===========================================================================
// Kernel 1 (R20 = R19 verbatim): stencil only, 512 blocks x 2 identity rows,
// coalesced row-major G16 write. R7-era evidence: ~15-17us standalone.
// ===========================================================================
__global__ __launch_bounds__(256, 2)
void precompute_G16(const float* __restrict__ diag,
                    const float* __restrict__ subpad,
                    const float* __restrict__ suppad,
                    const float* __restrict__ logit,
                    f16* __restrict__ G16)   // [k][s] row-major
{
    __shared__ float buf[2][2][SIZE];     // 16 KB

    const int tid = threadIdx.x;
    const int s0  = tid * 4;
    const int rowbase = blockIdx.x * 2;

    #pragma unroll
    for (int r = 0; r < 2; ++r) {
        float4 v;
        v.x = (rowbase + r == s0 + 0) ? 1.f : 0.f;
        v.y = (rowbase + r == s0 + 1) ? 1.f : 0.f;
        v.z = (rowbase + r == s0 + 2) ? 1.f : 0.f;
        v.w = (rowbase + r == s0 + 3) ? 1.f : 0.f;
        *(float4*)&buf[0][r][s0] = v;
    }
    __syncthreads();

    int cur = 0;
    for (int t = 0; t < NTERMS; ++t) {
        const int i = NTERMS - 1 - t;

        float lg[MM];
        float mx = -3.4e38f;
        #pragma unroll
        for (int j = 0; j < MM; ++j) { lg[j] = logit[i * MM + j]; mx = fmaxf(mx, lg[j]); }
        float ssum = 0.f;
        #pragma unroll
        for (int j = 0; j < MM; ++j) { lg[j] = __expf(lg[j] - mx); ssum += lg[j]; }
        const float inv = 1.0f / ssum;

        float D[4] = {0.f, 0.f, 0.f, 0.f};
        float Wsb[MM][4], Wsp[MM][4];
        #pragma unroll
        for (int j = 0; j < MM; ++j) {
            const float pj = lg[j] * inv;
            const float4 dg = ldq(diag   + j * SIZE + s0);
            const float4 sb = ldq(subpad + j * SIZE + s0);
            const float4 sp = ldq(suppad + j * SIZE + s0);
            D[0] = fmaf(pj, dg.x, D[0]); D[1] = fmaf(pj, dg.y, D[1]);
            D[2] = fmaf(pj, dg.z, D[2]); D[3] = fmaf(pj, dg.w, D[3]);
            Wsb[j][0] = pj * sb.x; Wsb[j][1] = pj * sb.y;
            Wsb[j][2] = pj * sb.z; Wsb[j][3] = pj * sb.w;
            Wsp[j][0] = pj * sp.x; Wsp[j][1] = pj * sp.y;
            Wsp[j][2] = pj * sp.z; Wsp[j][3] = pj * sp.w;
        }

        const bool last = (t == NTERMS - 1);
        for (int r = 0; r < 2; ++r) {
            const float* row = &buf[cur][r][0];

            const float4 xo = ldq(row + s0);
            float a0 = D[0] * xo.x, a1 = D[1] * xo.y,
                  a2 = D[2] * xo.z, a3 = D[3] * xo.w;

            const float4 xl = ldq(row + (s0 >= 4         ? s0 - 4 : 0));
            const float4 xr = ldq(row + (s0 + 4 <= 1020  ? s0 + 4 : 1020));

            FMA4F(Wsb[9], xl.w, xo.x, xo.y, xo.z)
            FMA4F(Wsp[9], xo.y, xo.z, xo.w, xr.x)
            FMA4F(Wsb[8], xl.z, xl.w, xo.x, xo.y)
            FMA4F(Wsp[8], xo.z, xo.w, xr.x, xr.y)
            FMA4F(Wsb[7], xl.x, xl.y, xl.z, xl.w)
            FMA4F(Wsp[7], xr.x, xr.y, xr.z, xr.w)
            #pragma unroll
            for (int j = 0; j <= 6; ++j) {
                const int d = 512 >> j;
                const float4 xm = ldq(row + (s0 >= d        ? s0 - d : 0));
                const float4 xp = ldq(row + (s0 + d <= 1020 ? s0 + d : 1020));
                FMA4F(Wsb[j], xm.x, xm.y, xm.z, xm.w)
                FMA4F(Wsp[j], xp.x, xp.y, xp.z, xp.w)
            }

            if (last) {
                const int k = rowbase + r;
                f16x4 h;
                h[0] = (f16)a0; h[1] = (f16)a1; h[2] = (f16)a2; h[3] = (f16)a3;
                *(f16x4*)(G16 + (long)k * SIZE + s0) = h;
            } else {
                *(float4*)&buf[cur ^ 1][r][s0] = make_float4(a0, a1, a2, a3);
            }
        }
        __syncthreads();
        cur ^= 1;
    }
}

// ===========================================================================
// Kernel 2 (R20 = R18 verbatim): Gt[s][k] = G16[k][s], 64x64 tiles, ~3us.
// ===========================================================================
__global__ __launch_bounds__(256)
void transpose16(const f16* __restrict__ G16, f16* __restrict__ Gt)
{
    __shared__ float tile[64][65];
    const int tid = threadIdx.x;
    const int k0 = blockIdx.x * 64;
    const int s0 = blockIdx.y * 64;
    const int rr = tid >> 4;
    const int cc = (tid & 15) * 4;

    #pragma unroll
    for (int p = 0; p < 4; ++p) {
        const f16x4 v = *(const f16x4*)(G16 + (long)(k0 + rr + p * 16) * SIZE + s0 + cc);
        tile[rr + p * 16][cc + 0] = (float)v[0];
        tile[rr + p * 16][cc + 1] = (float)v[1];
        tile[rr + p * 16][cc + 2] = (float)v[2];
        tile[rr + p * 16][cc + 3] = (float)v[3];
    }
    __syncthreads();
    #pragma unroll
    for (int p = 0; p < 4; ++p) {
        const int s = rr + p * 16;
        f16x4 h;
        h[0] = (f16)tile[cc + 0][s];
        h[1] = (f16)tile[cc + 1][s];
        h[2] = (f16)tile[cc + 2][s];
        h[3] = (f16)tile[cc + 3][s];
        *(f16x4*)(Gt + (long)(s0 + s) * SIZE + k0 + cc) = h;
    }
}

// ===========================================================================
// Kernel 3 (R20 = R9's gemm VERBATIM, measured 56-58us, absmax 0.0625):
// consumes fp32 x DIRECTLY (reg-staged A + inline cvt -> no xh pass, no
// cvt kernel, no xh writes). BM=BN=128, BK=32, PADK=36 (2-way free banks),
// B double-buffered in named regs from global (L2-resident Gt), bm-XCD
// swizzle (x panel fetched once: FETCH 25MB proven in R9).
// ===========================================================================
#define BMT 128
#define BNT 128
#define BKT 32
#define PADK 36
#define NKT (1024 / BKT)

__global__ __launch_bounds__(256, 2)
void gemm_f16(const float* __restrict__ x,
              const f16* __restrict__ Gt,
              float* __restrict__ out)
{
    __shared__ f16 Xs[2][BMT][PADK];   // 18 KB

    const int tid  = threadIdx.x;
    const int bm   = blockIdx.x & 63;          // same-bm -> same XCD
    const int bn   = blockIdx.x >> 6;
    const int w    = tid >> 6, lane = tid & 63;
    const int wm   = w >> 1,  wn   = w & 1;
    const int lr   = lane & 15, lk = lane >> 4;

    const int sr = tid >> 1;
    const int sk = (tid & 1) * 16;
    const float* xrow = x + (long)(bm * BMT + sr) * 1024 + sk;

    const f16* gbase = Gt + (long)(bn * BNT + wn * 64 + lr) * 1024 + lk * 8;

    f32x4 acc[4][4];
    #pragma unroll
    for (int mi = 0; mi < 4; ++mi)
        #pragma unroll
        for (int ni = 0; ni < 4; ++ni)
            acc[mi][ni] = (f32x4){0.f, 0.f, 0.f, 0.f};

    float4 v0, v1, v2, v3;
    f16x8 b0, b1, b2, b3;
    f16x8 c0, c1, c2, c3;

#define LOAD_A(KT) {                                                  \
        const float* xp = xrow + (KT) * BKT;                          \
        v0 = ldq(xp); v1 = ldq(xp + 4);                               \
        v2 = ldq(xp + 8); v3 = ldq(xp + 12); }
#define WRITE_A(BUF) {                                                \
        f16x8 h0, h1; cvt16(v0, v1, h0); cvt16(v2, v3, h1);           \
        *(f16x8*)&Xs[BUF][sr][sk]     = h0;                           \
        *(f16x8*)&Xs[BUF][sr][sk + 8] = h1; }
#define LOAD_B(B0, B1, B2, B3, KT) {                                  \
        const f16* gp = gbase + (KT) * BKT;                           \
        B0 = *(const f16x8*)(gp);                                     \
        B1 = *(const f16x8*)(gp + 16 * 1024);                         \
        B2 = *(const f16x8*)(gp + 32 * 1024);                         \
        B3 = *(const f16x8*)(gp + 48 * 1024); }
#define COMPUTE(BUF, B0, B1, B2, B3) {                                \
        f16x8 a0 = *(const f16x8*)&Xs[BUF][wm * 64 +  0 + lr][lk * 8];\
        f16x8 a1 = *(const f16x8*)&Xs[BUF][wm * 64 + 16 + lr][lk * 8];\
        f16x8 a2 = *(const f16x8*)&Xs[BUF][wm * 64 + 32 + lr][lk * 8];\
        f16x8 a3 = *(const f16x8*)&Xs[BUF][wm * 64 + 48 + lr][lk * 8];\
        acc[0][0] = __builtin_amdgcn_mfma_f32_16x16x32_f16(a0, B0, acc[0][0], 0, 0, 0); \
        acc[0][1] = __builtin_amdgcn_mfma_f32_16x16x32_f16(a0, B1, acc[0][1], 0, 0, 0); \
        acc[0][2] = __builtin_amdgcn_mfma_f32_16x16x32_f16(a0, B2, acc[0][2], 0, 0, 0); \
        acc[0][3] = __builtin_amdgcn_mfma_f32_16x16x32_f16(a0, B3, acc[0][3], 0, 0, 0); \
        acc[1][0] = __builtin_amdgcn_mfma_f32_16x16x32_f16(a1, B0, acc[1][0], 0, 0, 0); \
        acc[1][1] = __builtin_amdgcn_mfma_f32_16x16x32_f16(a1, B1, acc[1][1], 0, 0, 0); \
        acc[1][2] = __builtin_amdgcn_mfma_f32_16x16x32_f16(a1, B2, acc[1][2], 0, 0, 0); \
        acc[1][3] = __builtin_amdgcn_mfma_f32_16x16x32_f16(a1, B3, acc[1][3], 0, 0, 0); \
        acc[2][0] = __builtin_amdgcn_mfma_f32_16x16x32_f16(a2, B0, acc[2][0], 0, 0, 0); \
        acc[2][1] = __builtin_amdgcn_mfma_f32_16x16x32_f16(a2, B1, acc[2][1], 0, 0, 0); \
        acc[2][2] = __builtin_amdgcn_mfma_f32_16x16x32_f16(a2, B2, acc[2][2], 0, 0, 0); \
        acc[2][3] = __builtin_amdgcn_mfma_f32_16x16x32_f16(a2, B3, acc[2][3], 0, 0, 0); \
        acc[3][0] = __builtin_amdgcn_mfma_f32_16x16x32_f16(a3, B0, acc[3][0], 0, 0, 0); \
        acc[3][1] = __builtin_amdgcn_mfma_f32_16x16x32_f16(a3, B1, acc[3][1], 0, 0, 0); \
        acc[3][2] = __builtin_amdgcn_mfma_f32_16x16x32_f16(a3, B2, acc[3][2], 0, 0, 0); \
        acc[3][3] = __builtin_amdgcn_mfma_f32_16x16x32_f16(a3, B3, acc[3][3], 0, 0, 0); }

    LOAD_A(0); WRITE_A(0); LOAD_B(b0, b1, b2, b3, 0);
    __syncthreads();

    #pragma unroll 1
    for (int kt2 = 0; kt2 < NKT / 2; ++kt2) {
        const int kt = kt2 * 2;
        LOAD_A(kt + 1);
        LOAD_B(c0, c1, c2, c3, kt + 1);
        COMPUTE(0, b0, b1, b2, b3);
        WRITE_A(1);
        __syncthreads();
        if (kt2 < NKT / 2 - 1) {
            LOAD_A(kt + 2);
            LOAD_B(b0, b1, b2, b3, kt + 2);
        }
        COMPUTE(1, c0, c1, c2, c3);
        if (kt2 < NKT / 2 - 1) {
            WRITE_A(0);
        }
        __syncthreads();
    }

    const long orow0 = (long)bm * BMT + wm * 64 + lk * 4;
    const int  ocol0 = bn * BNT + wn * 64 + lr;
    #pragma unroll
    for (int mi = 0; mi < 4; ++mi)
        #pragma unroll
        for (int ni = 0; ni < 4; ++ni)
            #pragma unroll
            for (int q = 0; q < 4; ++q)
                out[(orow0 + mi * 16 + q) * 1024 + ocol0 + ni * 16] = acc[mi][ni][q];

#undef LOAD_A
#undef WRITE_A
#undef LOAD_B
#undef COMPUTE
}

// ===========================================================================
// Fallback (ws too small): R6's proven stencil kernel.
// ===========================================================================
#define RPB 16
#define MIX_L(acc, r32, ww) \
    asm("v_fma_mix_f32 %0, %1, %2, %0 op_sel:[0,0,0] op_sel_hi:[1,0,0]" \
        : "+v"(acc) : "v"(r32), "v"(ww))
#define MIX_H(acc, r32, ww) \
    asm("v_fma_mix_f32 %0, %1, %2, %0 op_sel:[1,0,0] op_sel_hi:[1,0,0]" \
        : "+v"(acc) : "v"(r32), "v"(ww))

__global__ __launch_bounds__(256, 2)
void butterfly_h16mix(const float* __restrict__ x,
                      const float* __restrict__ diag,
                      const float* __restrict__ subpad,
                      const float* __restrict__ suppad,
                      const float* __restrict__ logit,
                      float* __restrict__ out)
{
    __shared__ f16 buf[2][RPB][SIZE];
    const int tid = threadIdx.x;
    const int s0  = tid * 4;
    const long rowbase = (long)blockIdx.x * RPB;

    #pragma unroll
    for (int r = 0; r < RPB; ++r) {
        const float4 v = ldq(x + (rowbase + r) * SIZE + s0);
        f16x4 h;
        h[0] = (f16)v.x; h[1] = (f16)v.y; h[2] = (f16)v.z; h[3] = (f16)v.w;
        *(f16x4*)&buf[0][r][s0] = h;
    }
    __syncthreads();

    int cur = 0;
    for (int t = 0; t < NTERMS; ++t) {
        const int i = NTERMS - 1 - t;
        float lg[MM];
        float mx = -3.4e38f;
        #pragma unroll
        for (int j = 0; j < MM; ++j) { lg[j] = logit[i * MM + j]; mx = fmaxf(mx, lg[j]); }
        float ssum = 0.f;
        #pragma unroll
        for (int j = 0; j < MM; ++j) { lg[j] = __expf(lg[j] - mx); ssum += lg[j]; }
        const float inv = 1.0f / ssum;

        float D[4] = {0.f, 0.f, 0.f, 0.f};
        float Wsb[MM][4], Wsp[MM][4];
        #pragma unroll
        for (int j = 0; j < MM; ++j) {
            const float pj = lg[j] * inv;
            const float4 dg = ldq(diag   + j * SIZE + s0);
            const float4 sb = ldq(subpad + j * SIZE + s0);
            const float4 sp = ldq(suppad + j * SIZE + s0);
            D[0] = fmaf(pj, dg.x, D[0]); D[1] = fmaf(pj, dg.y, D[1]);
            D[2] = fmaf(pj, dg.z, D[2]); D[3] = fmaf(pj, dg.w, D[3]);
            Wsb[j][0] = pj * sb.x; Wsb[j][1] = pj * sb.y;
            Wsb[j][2] = pj * sb.z; Wsb[j][3] = pj * sb.w;
            Wsp[j][0] = pj * sp.x; Wsp[j][1] = pj * sp.y;
            Wsp[j][2] = pj * sp.z; Wsp[j][3] = pj * sp.w;
        }

        const bool last = (t == NTERMS - 1);
        for (int r = 0; r < RPB; ++r) {
            const f16* row = &buf[cur][r][0];
            const i2 xo = *(const i2*)&row[s0];
            const i2 xl = *(const i2*)&row[(s0 >= 4)        ? s0 - 4 : 0];
            const i2 xr = *(const i2*)&row[(s0 + 4 <= 1020) ? s0 + 4 : 1020];
            float a0 = 0.f, a1 = 0.f, a2 = 0.f, a3 = 0.f;

            MIX_L(a0, xo.x, D[0]); MIX_H(a1, xo.x, D[1]);
            MIX_L(a2, xo.y, D[2]); MIX_H(a3, xo.y, D[3]);
            MIX_H(a0, xl.y, Wsb[9][0]); MIX_L(a1, xo.x, Wsb[9][1]);
            MIX_H(a2, xo.x, Wsb[9][2]); MIX_L(a3, xo.y, Wsb[9][3]);
            MIX_H(a0, xo.x, Wsp[9][0]); MIX_L(a1, xo.y, Wsp[9][1]);
            MIX_H(a2, xo.y, Wsp[9][2]); MIX_L(a3, xr.x, Wsp[9][3]);
            MIX_L(a0, xl.y, Wsb[8][0]); MIX_H(a1, xl.y, Wsb[8][1]);
            MIX_L(a2, xo.x, Wsb[8][2]); MIX_H(a3, xo.x, Wsb[8][3]);
            MIX_L(a0, xo.y, Wsp[8][0]); MIX_H(a1, xo.y, Wsp[8][1]);
            MIX_L(a2, xr.x, Wsp[8][2]); MIX_H(a3, xr.x, Wsp[8][3]);
            MIX_L(a0, xl.x, Wsb[7][0]); MIX_H(a1, xl.x, Wsb[7][1]);
            MIX_L(a2, xl.y, Wsb[7][2]); MIX_H(a3, xl.y, Wsb[7][3]);
            MIX_L(a0, xr.x, Wsp[7][0]); MIX_H(a1, xr.x, Wsp[7][1]);
            MIX_L(a2, xr.y, Wsp[7][2]); MIX_H(a3, xr.y, Wsp[7][3]);
            #pragma unroll
            for (int j = 0; j <= 6; ++j) {
                const int d = 512 >> j;
                const i2 xm = *(const i2*)&row[(s0 >= d)        ? s0 - d : 0];
                const i2 xp = *(const i2*)&row[(s0 + d <= 1020) ? s0 + d : 1020];
                MIX_L(a0, xm.x, Wsb[j][0]); MIX_H(a1, xm.x, Wsb[j][1]);
                MIX_L(a2, xm.y, Wsb[j][2]); MIX_H(a3, xm.y, Wsb[j][3]);
                MIX_L(a0, xp.x, Wsp[j][0]); MIX_H(a1, xp.x, Wsp[j][1]);
                MIX_L(a2, xp.y, Wsp[j][2]); MIX_H(a3, xp.y, Wsp[j][3]);
            }

            if (last) {
                *(float4*)(out + (rowbase + r) * SIZE + s0) =
                    make_float4(a0, a1, a2, a3);
            } else {
                f16x4 hv;
                hv[0] = (f16)a0; hv[1] = (f16)a1; hv[2] = (f16)a2; hv[3] = (f16)a3;
                *(f16x4*)&buf[cur ^ 1][r][s0] = hv;
            }
        }
        __syncthreads();
        cur ^= 1;
    }
}

extern "C" void kernel_launch(void* const* d_in, const int* in_sizes, int n_in,
                              void* d_out, int out_size, void* d_ws, size_t ws_size,
                              hipStream_t stream) {
    const float* x      = (const float*)d_in[0];
    const float* diag   = (const float*)d_in[1];
    const float* subpad = (const float*)d_in[2];
    const float* suppad = (const float*)d_in[3];
    const float* logit  = (const float*)d_in[4];
    float* outp = (float*)d_out;

    const int batch = in_sizes[0] / SIZE;                        // 8192
    const size_t needG16 = (size_t)SIZE * SIZE * sizeof(f16);    // 2 MB
    const size_t needGt  = (size_t)SIZE * SIZE * sizeof(f16);    // 2 MB

    if (d_ws != nullptr && ws_size >= needG16 + needGt) {
        f16* G16 = (f16*)d_ws;
        f16* Gt  = (f16*)((char*)d_ws + needG16);
        precompute_G16<<<dim3(512), dim3(256), 0, stream>>>(
            diag, subpad, suppad, logit, G16);
        transpose16<<<dim3(16, 16), dim3(256), 0, stream>>>(G16, Gt);
        const int nblocks = (batch / BMT) * (SIZE / BNT);        // 512
        gemm_f16<<<dim3(nblocks), dim3(256), 0, stream>>>(x, Gt, outp);
    } else {
        butterfly_h16mix<<<dim3(batch / RPB), dim3(256), 0, stream>>>(
            x, diag, subpad, suppad, logit, outp);
    }
}

// Round 21
// 82.306 us; speedup vs baseline: 1.0604x; 1.0414x over previous
//
#include <hip/hip_runtime.h>

#define SIZE 1024
#define MM 10
#define NTERMS 10

typedef _Float16 f16;
typedef __attribute__((ext_vector_type(8))) _Float16 f16x8;
typedef __attribute__((ext_vector_type(4))) _Float16 f16x4;
typedef __attribute__((ext_vector_type(4))) float    f32x4;
typedef __attribute__((ext_vector_type(2))) int      i2;

typedef const __attribute__((address_space(1))) _Float16 gf16;  // global
typedef __attribute__((address_space(3))) _Float16 sf16;        // LDS

__device__ __forceinline__ float4 ldq(const float* p) { return *(const float4*)p; }

#define FMA4F(W, v0, v1, v2, v3)                                     \
    a0 = fmaf((W)[0], (v0), a0); a1 = fmaf((W)[1], (v1), a1);        \
    a2 = fmaf((W)[2], (v2), a2); a3 = fmaf((W)[3], (v3), a3);

__device__ __forceinline__ void cvt16(const float4& v0, const float4& v1, f16x8& h) {
    h[0] = (f16)v0.x; h[1] = (f16)v0.y; h[2] = (f16)v0.z; h[3] = (f16)v0.w;
    h[4] = (f16)v1.x; h[5] = (f16)v1.y; h[6] = (f16)v1.z; h[7] = (f16)v1.w;
}

// ===========================================================================
// R21 = R13 VERBATIM (best measured total: 82.03us, absmax 0.0625).
// fused_pre: blocks 0..511 = stencil (Gt scatter), blocks 512+ = cvt x->xh.
// gemm64: 1-wave 64x64 blocks, gload_lds A-staging, B-from-global regs,
// 2048 blocks, bm-XCD swizzle.
// 21-round search summary: gemm floor 45-49us across 6 structures
// (sync x3, BK x2, occupancy x2, no-xh); pre-chain floor ~33us across 7
// pairings. This config is the measured optimum of the decomposition.
// ===========================================================================
__global__ __launch_bounds__(256, 2)
void fused_pre(const float* __restrict__ x,
               const float* __restrict__ diag,
               const float* __restrict__ subpad,
               const float* __restrict__ suppad,
               const float* __restrict__ logit,
               f16* __restrict__ Gt,
               f16* __restrict__ xh)
{
    __shared__ float buf[2][2][SIZE];     // 16 KB (precompute branch only)

    const int tid = threadIdx.x;

    if (blockIdx.x >= 512) {
        const long i = ((long)(blockIdx.x - 512) * 256 + tid) * 16;
        const float4 a = ldq(x + i), b = ldq(x + i + 4),
                     c = ldq(x + i + 8), d = ldq(x + i + 12);
        f16x8 h0, h1; cvt16(a, b, h0); cvt16(c, d, h1);
        *(f16x8*)(xh + i)     = h0;
        *(f16x8*)(xh + i + 8) = h1;
        return;
    }

    const int s0  = tid * 4;
    const int rowbase = blockIdx.x * 2;

    #pragma unroll
    for (int r = 0; r < 2; ++r) {
        float4 v;
        v.x = (rowbase + r == s0 + 0) ? 1.f : 0.f;
        v.y = (rowbase + r == s0 + 1) ? 1.f : 0.f;
        v.z = (rowbase + r == s0 + 2) ? 1.f : 0.f;
        v.w = (rowbase + r == s0 + 3) ? 1.f : 0.f;
        *(float4*)&buf[0][r][s0] = v;
    }
    __syncthreads();

    int cur = 0;
    for (int t = 0; t < NTERMS; ++t) {
        const int i = NTERMS - 1 - t;

        float lg[MM];
        float mx = -3.4e38f;
        #pragma unroll
        for (int j = 0; j < MM; ++j) { lg[j] = logit[i * MM + j]; mx = fmaxf(mx, lg[j]); }
        float ssum = 0.f;
        #pragma unroll
        for (int j = 0; j < MM; ++j) { lg[j] = __expf(lg[j] - mx); ssum += lg[j]; }
        const float inv = 1.0f / ssum;

        float D[4] = {0.f, 0.f, 0.f, 0.f};
        float Wsb[MM][4], Wsp[MM][4];
        #pragma unroll
        for (int j = 0; j < MM; ++j) {
            const float pj = lg[j] * inv;
            const float4 dg = ldq(diag   + j * SIZE + s0);
            const float4 sb = ldq(subpad + j * SIZE + s0);
            const float4 sp = ldq(suppad + j * SIZE + s0);
            D[0] = fmaf(pj, dg.x, D[0]); D[1] = fmaf(pj, dg.y, D[1]);
            D[2] = fmaf(pj, dg.z, D[2]); D[3] = fmaf(pj, dg.w, D[3]);
            Wsb[j][0] = pj * sb.x; Wsb[j][1] = pj * sb.y;
            Wsb[j][2] = pj * sb.z; Wsb[j][3] = pj * sb.w;
            Wsp[j][0] = pj * sp.x; Wsp[j][1] = pj * sp.y;
            Wsp[j][2] = pj * sp.z; Wsp[j][3] = pj * sp.w;
        }

        const bool last = (t == NTERMS - 1);
        for (int r = 0; r < 2; ++r) {
            const float* row = &buf[cur][r][0];

            const float4 xo = ldq(row + s0);
            float a0 = D[0] * xo.x, a1 = D[1] * xo.y,
                  a2 = D[2] * xo.z, a3 = D[3] * xo.w;

            const float4 xl = ldq(row + (s0 >= 4         ? s0 - 4 : 0));
            const float4 xr = ldq(row + (s0 + 4 <= 1020  ? s0 + 4 : 1020));

            FMA4F(Wsb[9], xl.w, xo.x, xo.y, xo.z)
            FMA4F(Wsp[9], xo.y, xo.z, xo.w, xr.x)
            FMA4F(Wsb[8], xl.z, xl.w, xo.x, xo.y)
            FMA4F(Wsp[8], xo.z, xo.w, xr.x, xr.y)
            FMA4F(Wsb[7], xl.x, xl.y, xl.z, xl.w)
            FMA4F(Wsp[7], xr.x, xr.y, xr.z, xr.w)
            #pragma unroll
            for (int j = 0; j <= 6; ++j) {
                const int d = 512 >> j;
                const float4 xm = ldq(row + (s0 >= d        ? s0 - d : 0));
                const float4 xp = ldq(row + (s0 + d <= 1020 ? s0 + d : 1020));
                FMA4F(Wsb[j], xm.x, xm.y, xm.z, xm.w)
                FMA4F(Wsp[j], xp.x, xp.y, xp.z, xp.w)
            }

            if (last) {
                const int k = rowbase + r;
                Gt[(long)(s0 + 0) * SIZE + k] = (f16)a0;
                Gt[(long)(s0 + 1) * SIZE + k] = (f16)a1;
                Gt[(long)(s0 + 2) * SIZE + k] = (f16)a2;
                Gt[(long)(s0 + 3) * SIZE + k] = (f16)a3;
            } else {
                *(float4*)&buf[cur ^ 1][r][s0] = make_float4(a0, a1, a2, a3);
            }
        }
        __syncthreads();
        cur ^= 1;
    }
}

#define NKT 32

__global__ __launch_bounds__(64)
void gemm64(const f16* __restrict__ xh,
            const f16* __restrict__ Gt,
            float* __restrict__ out)
{
    __shared__ f16 Xs[2][64][32];      // 8 KB, linear

    const int lane = threadIdx.x;      // one wave
    const int bm   = blockIdx.x & 127; // 128 M-tiles; same-bm -> same XCD
    const int bn   = blockIdx.x >> 7;  // 16 N-tiles
    const int lr   = lane & 15, lk = lane >> 4;

    const f16* gsrc = xh + (long)(bm * 64 + (lane >> 2)) * 1024 + (lane & 3) * 8;
    const f16* gbase = Gt + (long)(bn * 64 + lr) * 1024 + lk * 8;

    f32x4 acc[4][4];
    #pragma unroll
    for (int mi = 0; mi < 4; ++mi)
        #pragma unroll
        for (int ni = 0; ni < 4; ++ni)
            acc[mi][ni] = (f32x4){0.f, 0.f, 0.f, 0.f};

    f16x8 b0, b1, b2, b3;
    f16x8 c0, c1, c2, c3;

#define STAGE(BUF, KT) {                                                      \
        const f16* gp = gsrc + (KT) * 32;                                     \
        sf16* lp = (sf16*)&Xs[BUF][0][0];                                     \
        __builtin_amdgcn_global_load_lds((gf16*)gp,               lp,        16, 0, 0); \
        __builtin_amdgcn_global_load_lds((gf16*)(gp + 16 * 1024), lp +  512, 16, 0, 0); \
        __builtin_amdgcn_global_load_lds((gf16*)(gp + 32 * 1024), lp + 1024, 16, 0, 0); \
        __builtin_amdgcn_global_load_lds((gf16*)(gp + 48 * 1024), lp + 1536, 16, 0, 0); }
#define LOAD_B(B0, B1, B2, B3, KT) {                                  \
        const f16* gp = gbase + (KT) * 32;                            \
        B0 = *(const f16x8*)(gp);                                     \
        B1 = *(const f16x8*)(gp + 16 * 1024);                         \
        B2 = *(const f16x8*)(gp + 32 * 1024);                         \
        B3 = *(const f16x8*)(gp + 48 * 1024); }
#define COMPUTE(BUF, B0, B1, B2, B3) {                                \
        f16x8 a0 = *(const f16x8*)&Xs[BUF][ 0 + lr][lk * 8];          \
        f16x8 a1 = *(const f16x8*)&Xs[BUF][16 + lr][lk * 8];          \
        f16x8 a2 = *(const f16x8*)&Xs[BUF][32 + lr][lk * 8];          \
        f16x8 a3 = *(const f16x8*)&Xs[BUF][48 + lr][lk * 8];          \
        acc[0][0] = __builtin_amdgcn_mfma_f32_16x16x32_f16(a0, B0, acc[0][0], 0, 0, 0); \
        acc[0][1] = __builtin_amdgcn_mfma_f32_16x16x32_f16(a0, B1, acc[0][1], 0, 0, 0); \
        acc[0][2] = __builtin_amdgcn_mfma_f32_16x16x32_f16(a0, B2, acc[0][2], 0, 0, 0); \
        acc[0][3] = __builtin_amdgcn_mfma_f32_16x16x32_f16(a0, B3, acc[0][3], 0, 0, 0); \
        acc[1][0] = __builtin_amdgcn_mfma_f32_16x16x32_f16(a1, B0, acc[1][0], 0, 0, 0); \
        acc[1][1] = __builtin_amdgcn_mfma_f32_16x16x32_f16(a1, B1, acc[1][1], 0, 0, 0); \
        acc[1][2] = __builtin_amdgcn_mfma_f32_16x16x32_f16(a1, B2, acc[1][2], 0, 0, 0); \
        acc[1][3] = __builtin_amdgcn_mfma_f32_16x16x32_f16(a1, B3, acc[1][3], 0, 0, 0); \
        acc[2][0] = __builtin_amdgcn_mfma_f32_16x16x32_f16(a2, B0, acc[2][0], 0, 0, 0); \
        acc[2][1] = __builtin_amdgcn_mfma_f32_16x16x32_f16(a2, B1, acc[2][1], 0, 0, 0); \
        acc[2][2] = __builtin_amdgcn_mfma_f32_16x16x32_f16(a2, B2, acc[2][2], 0, 0, 0); \
        acc[2][3] = __builtin_amdgcn_mfma_f32_16x16x32_f16(a2, B3, acc[2][3], 0, 0, 0); \
        acc[3][0] = __builtin_amdgcn_mfma_f32_16x16x32_f16(a3, B0, acc[3][0], 0, 0, 0); \
        acc[3][1] = __builtin_amdgcn_mfma_f32_16x16x32_f16(a3, B1, acc[3][1], 0, 0, 0); \
        acc[3][2] = __builtin_amdgcn_mfma_f32_16x16x32_f16(a3, B2, acc[3][2], 0, 0, 0); \
        acc[3][3] = __builtin_amdgcn_mfma_f32_16x16x32_f16(a3, B3, acc[3][3], 0, 0, 0); }

    STAGE(0, 0); LOAD_B(b0, b1, b2, b3, 0);
    __syncthreads();

    #pragma unroll 1
    for (int kt2 = 0; kt2 < NKT / 2; ++kt2) {
        const int kt = kt2 * 2;
        STAGE(1, kt + 1);
        LOAD_B(c0, c1, c2, c3, kt + 1);
        COMPUTE(0, b0, b1, b2, b3);
        __syncthreads();
        if (kt2 < NKT / 2 - 1) {
            STAGE(0, kt + 2);
            LOAD_B(b0, b1, b2, b3, kt + 2);
        }
        COMPUTE(1, c0, c1, c2, c3);
        __syncthreads();
    }

    const long orow0 = (long)bm * 64 + lk * 4;
    const int  ocol0 = bn * 64 + lr;
    #pragma unroll
    for (int mi = 0; mi < 4; ++mi)
        #pragma unroll
        for (int ni = 0; ni < 4; ++ni)
            #pragma unroll
            for (int q = 0; q < 4; ++q)
                out[(orow0 + mi * 16 + q) * 1024 + ocol0 + ni * 16] = acc[mi][ni][q];

#undef STAGE
#undef LOAD_B
#undef COMPUTE
}

// ===========================================================================
// Fallback (ws too small): R6's proven stencil kernel.
// ===========================================================================
#define RPB 16
#define MIX_L(acc, r32, ww) \
    asm("v_fma_mix_f32 %0, %1, %2, %0 op_sel:[0,0,0] op_sel_hi:[1,0,0]" \
        : "+v"(acc) : "v"(r32), "v"(ww))
#define MIX_H(acc, r32, ww) \
    asm("v_fma_mix_f32 %0, %1, %2, %0 op_sel:[1,0,0] op_sel_hi:[1,0,0]" \
        : "+v"(acc) : "v"(r32), "v"(ww))

__global__ __launch_bounds__(256, 2)
void butterfly_h16mix(const float* __restrict__ x,
                      const float* __restrict__ diag,
                      const float* __restrict__ subpad,
                      const float* __restrict__ suppad,
                      const float* __restrict__ logit,
                      float* __restrict__ out)
{
    __shared__ f16 buf[2][RPB][SIZE];
    const int tid = threadIdx.x;
    const int s0  = tid * 4;
    const long rowbase = (long)blockIdx.x * RPB;

    #pragma unroll
    for (int r = 0; r < RPB; ++r) {
        const float4 v = ldq(x + (rowbase + r) * SIZE + s0);
        f16x4 h;
        h[0] = (f16)v.x; h[1] = (f16)v.y; h[2] = (f16)v.z; h[3] = (f16)v.w;
        *(f16x4*)&buf[0][r][s0] = h;
    }
    __syncthreads();

    int cur = 0;
    for (int t = 0; t < NTERMS; ++t) {
        const int i = NTERMS - 1 - t;
        float lg[MM];
        float mx = -3.4e38f;
        #pragma unroll
        for (int j = 0; j < MM; ++j) { lg[j] = logit[i * MM + j]; mx = fmaxf(mx, lg[j]); }
        float ssum = 0.f;
        #pragma unroll
        for (int j = 0; j < MM; ++j) { lg[j] = __expf(lg[j] - mx); ssum += lg[j]; }
        const float inv = 1.0f / ssum;

        float D[4] = {0.f, 0.f, 0.f, 0.f};
        float Wsb[MM][4], Wsp[MM][4];
        #pragma unroll
        for (int j = 0; j < MM; ++j) {
            const float pj = lg[j] * inv;
            const float4 dg = ldq(diag   + j * SIZE + s0);
            const float4 sb = ldq(subpad + j * SIZE + s0);
            const float4 sp = ldq(suppad + j * SIZE + s0);
            D[0] = fmaf(pj, dg.x, D[0]); D[1] = fmaf(pj, dg.y, D[1]);
            D[2] = fmaf(pj, dg.z, D[2]); D[3] = fmaf(pj, dg.w, D[3]);
            Wsb[j][0] = pj * sb.x; Wsb[j][1] = pj * sb.y;
            Wsb[j][2] = pj * sb.z; Wsb[j][3] = pj * sb.w;
            Wsp[j][0] = pj * sp.x; Wsp[j][1] = pj * sp.y;
            Wsp[j][2] = pj * sp.z; Wsp[j][3] = pj * sp.w;
        }

        const bool last = (t == NTERMS - 1);
        for (int r = 0; r < RPB; ++r) {
            const f16* row = &buf[cur][r][0];
            const i2 xo = *(const i2*)&row[s0];
            const i2 xl = *(const i2*)&row[(s0 >= 4)        ? s0 - 4 : 0];
            const i2 xr = *(const i2*)&row[(s0 + 4 <= 1020) ? s0 + 4 : 1020];
            float a0 = 0.f, a1 = 0.f, a2 = 0.f, a3 = 0.f;

            MIX_L(a0, xo.x, D[0]); MIX_H(a1, xo.x, D[1]);
            MIX_L(a2, xo.y, D[2]); MIX_H(a3, xo.y, D[3]);
            MIX_H(a0, xl.y, Wsb[9][0]); MIX_L(a1, xo.x, Wsb[9][1]);
            MIX_H(a2, xo.x, Wsb[9][2]); MIX_L(a3, xo.y, Wsb[9][3]);
            MIX_H(a0, xo.x, Wsp[9][0]); MIX_L(a1, xo.y, Wsp[9][1]);
            MIX_H(a2, xo.y, Wsp[9][2]); MIX_L(a3, xr.x, Wsp[9][3]);
            MIX_L(a0, xl.y, Wsb[8][0]); MIX_H(a1, xl.y, Wsb[8][1]);
            MIX_L(a2, xo.x, Wsb[8][2]); MIX_H(a3, xo.x, Wsb[8][3]);
            MIX_L(a0, xo.y, Wsp[8][0]); MIX_H(a1, xo.y, Wsp[8][1]);
            MIX_L(a2, xr.x, Wsp[8][2]); MIX_H(a3, xr.x, Wsp[8][3]);
            MIX_L(a0, xl.x, Wsb[7][0]); MIX_H(a1, xl.x, Wsb[7][1]);
            MIX_L(a2, xl.y, Wsb[7][2]); MIX_H(a3, xl.y, Wsb[7][3]);
            MIX_L(a0, xr.x, Wsp[7][0]); MIX_H(a1, xr.x, Wsp[7][1]);
            MIX_L(a2, xr.y, Wsp[7][2]); MIX_H(a3, xr.y, Wsp[7][3]);
            #pragma unroll
            for (int j = 0; j <= 6; ++j) {
                const int d = 512 >> j;
                const i2 xm = *(const i2*)&row[(s0 >= d)        ? s0 - d : 0];
                const i2 xp = *(const i2*)&row[(s0 + d <= 1020) ? s0 + d : 1020];
                MIX_L(a0, xm.x, Wsb[j][0]); MIX_H(a1, xm.x, Wsb[j][1]);
                MIX_L(a2, xm.y, Wsb[j][2]); MIX_H(a3, xm.y, Wsb[j][3]);
                MIX_L(a0, xp.x, Wsp[j][0]); MIX_H(a1, xp.x, Wsp[j][1]);
                MIX_L(a2, xp.y, Wsp[j][2]); MIX_H(a3, xp.y, Wsp[j][3]);
            }

            if (last) {
                *(float4*)(out + (rowbase + r) * SIZE + s0) =
                    make_float4(a0, a1, a2, a3);
            } else {
                f16x4 hv;
                hv[0] = (f16)a0; hv[1] = (f16)a1; hv[2] = (f16)a2; hv[3] = (f16)a3;
                *(f16x4*)&buf[cur ^ 1][r][s0] = hv;
            }
        }
        __syncthreads();
        cur ^= 1;
    }
}

extern "C" void kernel_launch(void* const* d_in, const int* in_sizes, int n_in,
                              void* d_out, int out_size, void* d_ws, size_t ws_size,
                              hipStream_t stream) {
    const float* x      = (const float*)d_in[0];
    const float* diag   = (const float*)d_in[1];
    const float* subpad = (const float*)d_in[2];
    const float* suppad = (const float*)d_in[3];
    const float* logit  = (const float*)d_in[4];
    float* outp = (float*)d_out;

    const int batch = in_sizes[0] / SIZE;                        // 8192
    const size_t needGt = (size_t)SIZE * SIZE * sizeof(f16);     // 2 MB
    const size_t needXh = (size_t)batch * SIZE * sizeof(f16);    // 16 MB

    if (d_ws != nullptr && ws_size >= needGt + needXh) {
        f16* Gt = (f16*)d_ws;
        f16* xh = (f16*)((char*)d_ws + needGt);
        const int cvtBlocks = (int)(((long)batch * SIZE) / (256 * 16));  // 2048
        fused_pre<<<dim3(512 + cvtBlocks), dim3(256), 0, stream>>>(
            x, diag, subpad, suppad, logit, Gt, xh);
        const int nblocks = (batch / 64) * (SIZE / 64);          // 128*16 = 2048
        gemm64<<<dim3(nblocks), dim3(64), 0, stream>>>(xh, Gt, outp);
    } else {
        butterfly_h16mix<<<dim3(batch / RPB), dim3(256), 0, stream>>>(
            x, diag, subpad, suppad, logit, outp);
    }
}